// Round 1
// baseline (942.211 us; speedup 1.0000x reference)
//
#include <hip/hip_runtime.h>

#define NL   8
#define DIM  2048
#define NH   8
#define NKV  2
#define HD   256
#define KVL  4096
#define FFI  8192
#define PLD  256
#define POS  2047
#define NCH  128   // attention chunks over 2048 valid positions
#define CP   16    // positions per chunk

__device__ __forceinline__ float waveAllSum(float v){
#pragma unroll
  for(int o=1;o<64;o<<=1) v += __shfl_xor(v,o,64);
  return v;
}

__device__ __forceinline__ float blockSum256(float v, float* red){
  int lane = threadIdx.x & 63, w = threadIdx.x >> 6;
  v = waveAllSum(v);
  __syncthreads();
  if(lane==0) red[w] = v;
  __syncthreads();
  return red[0]+red[1]+red[2]+red[3];
}

__device__ __forceinline__ float gelu_tanh(float v){
  return 0.5f*v*(1.0f + tanhf(0.7978845608028654f*(v + 0.044715f*v*v*v)));
}

// ---- initial: h = hidden; x = rms(h)*g_in ----
__global__ __launch_bounds__(256) void initial_k(const float* __restrict__ hidden,
    const float* __restrict__ gin, float* __restrict__ h, float* __restrict__ x){
  __shared__ float red[4];
  int tid = threadIdx.x;
  float v[8]; float ss = 0.f;
#pragma unroll
  for(int i=0;i<8;i++){ v[i] = hidden[tid + i*256]; ss += v[i]*v[i]; }
  ss = blockSum256(ss, red);
  float r = rsqrtf(ss*(1.f/DIM) + 1e-6f);
#pragma unroll
  for(int i=0;i<8;i++){ int idx = tid + i*256; h[idx] = v[i]; x[idx] = v[i]*r*gin[idx]; }
}

// ---- generic GEMV: y[r] = W[r,:] . x, row-major W, one row per wave ----
template<int C>
__global__ __launch_bounds__(256) void gemv_k(const float* __restrict__ W,
    const float* __restrict__ x, float* __restrict__ y, int R){
  __shared__ float xs[C];
  for(int i=threadIdx.x; i<C/4; i+=256)
    ((float4*)xs)[i] = ((const float4*)x)[i];
  __syncthreads();
  int lane = threadIdx.x & 63, wv = threadIdx.x >> 6;
  int r = blockIdx.x*4 + wv;
  if(r >= R) return;
  const float4* Wr = (const float4*)(W + (size_t)r*C);
  float acc = 0.f;
#pragma unroll
  for(int i=0;i<C/256;i++){
    float4 a = Wr[lane + i*64];
    float4 b = ((float4*)xs)[lane + i*64];
    acc += a.x*b.x + a.y*b.y + a.z*b.z + a.w*b.w;
  }
  acc = waveAllSum(acc);
  if(lane==0) y[r] = acc;
}

// ---- fused QKV GEMV: rows [0,2048)=w_q, [2048,2560)=w_k, [2560,3072)=w_v ----
__global__ __launch_bounds__(256) void qkv_k(const float* __restrict__ Wq,
    const float* __restrict__ Wk, const float* __restrict__ Wv,
    const float* __restrict__ x, float* __restrict__ qkv){
  __shared__ float xs[DIM];
  for(int i=threadIdx.x; i<DIM/4; i+=256)
    ((float4*)xs)[i] = ((const float4*)x)[i];
  __syncthreads();
  int lane = threadIdx.x & 63, wv = threadIdx.x >> 6;
  int r = blockIdx.x*4 + wv;
  const float* W; int row;
  if(r < 2048){ W = Wq; row = r; }
  else if(r < 2560){ W = Wk; row = r - 2048; }
  else { W = Wv; row = r - 2560; }
  const float4* Wr = (const float4*)(W + (size_t)row*DIM);
  float acc = 0.f;
#pragma unroll
  for(int i=0;i<DIM/256;i++){
    float4 a = Wr[lane + i*64];
    float4 b = ((float4*)xs)[lane + i*64];
    acc += a.x*b.x + a.y*b.y + a.z*b.z + a.w*b.w;
  }
  acc = waveAllSum(acc);
  if(lane==0) qkv[r] = acc;
}

// ---- per-head rms(+gain)(+rope); write q to ws, k/v into output caches at POS ----
__global__ __launch_bounds__(256) void qkvnorm_k(const float* __restrict__ qkv,
    const float* __restrict__ gq, const float* __restrict__ gk,
    const float* __restrict__ cosT, const float* __restrict__ sinT,
    float* __restrict__ qout, float* __restrict__ Kl, float* __restrict__ Vl){
  __shared__ float buf[256];
  __shared__ float red[4];
  int b = blockIdx.x, d = threadIdx.x;
  const float* src; float* dst; int mode;
  if(b < 8){ src = qkv + b*256; dst = qout + b*256; mode = 0; }
  else if(b < 10){ int kvh = b-8;  src = qkv + 2048 + kvh*256; dst = Kl + ((size_t)kvh*KVL + POS)*HD; mode = 1; }
  else           { int kvh = b-10; src = qkv + 2560 + kvh*256; dst = Vl + ((size_t)kvh*KVL + POS)*HD; mode = 2; }
  float val = src[d];
  buf[d] = val;
  float ss = blockSum256(val*val, red);
  float scale = rsqrtf(ss*(1.f/HD) + 1e-6f);
  float outv;
  if(mode == 2){
    outv = val*scale;
  } else {
    const float* g = (mode==0) ? gq : gk;
    float n = val*scale*g[d];
    int pd = d ^ 128;
    float np = buf[pd]*scale*g[pd];
    outv = n*cosT[d] + ((d < 128) ? -np : np)*sinT[d];
  }
  dst[d] = outv;
}

// ---- attention partials: block = (kv, chunk); 4 q-heads share K/V reads ----
__global__ __launch_bounds__(256) void attn_partial_k(const float* __restrict__ q,
    const float* __restrict__ Kl, const float* __restrict__ Vl,
    float* __restrict__ pm, float* __restrict__ pl, float* __restrict__ po){
  int b = blockIdx.x;
  int kv = b / NCH, c = b % NCH;
  int lane = threadIdx.x & 63, wv = threadIdx.x >> 6;
  __shared__ float s_s[4][CP];
  __shared__ float s_w[4][CP];
  float4 q4[4];
  const float4* qp = (const float4*)(q + kv*4*HD);
#pragma unroll
  for(int hh=0;hh<4;hh++) q4[hh] = qp[hh*64 + lane];
  const float4* Kp = (const float4*)(Kl + ((size_t)kv*KVL + c*CP)*HD);
#pragma unroll
  for(int j=0;j<4;j++){
    int p = wv*4 + j;
    float4 k4 = Kp[(size_t)p*64 + lane];
    float dt[4];
#pragma unroll
    for(int hh=0;hh<4;hh++)
      dt[hh] = k4.x*q4[hh].x + k4.y*q4[hh].y + k4.z*q4[hh].z + k4.w*q4[hh].w;
#pragma unroll
    for(int hh=0;hh<4;hh++) dt[hh] = waveAllSum(dt[hh]);
    if(lane==0){
#pragma unroll
      for(int hh=0;hh<4;hh++) s_s[hh][p] = dt[hh];
    }
  }
  __syncthreads();
  if(threadIdx.x < 4){
    int hh = threadIdx.x;
    float m = -1e30f;
    for(int p=0;p<CP;p++) m = fmaxf(m, s_s[hh][p]);
    float lsum = 0.f;
    for(int p=0;p<CP;p++){ float e = expf(s_s[hh][p]-m); s_w[hh][p]=e; lsum += e; }
    int hg = kv*4 + hh;
    pm[hg*NCH + c] = m;
    pl[hg*NCH + c] = lsum;
  }
  __syncthreads();
  int d = threadIdx.x;
  float acc[4] = {0.f,0.f,0.f,0.f};
  const float* Vp = Vl + ((size_t)kv*KVL + c*CP)*HD;
  for(int p=0;p<CP;p++){
    float vv = Vp[p*HD + d];
#pragma unroll
    for(int hh=0;hh<4;hh++) acc[hh] += s_w[hh][p]*vv;
  }
#pragma unroll
  for(int hh=0;hh<4;hh++){
    int hg = kv*4 + hh;
    po[((size_t)hg*NCH + c)*HD + d] = acc[hh];
  }
}

// ---- combine chunk partials -> ao[h*256+d] ----
__global__ __launch_bounds__(256) void attn_combine_k(const float* __restrict__ pm,
    const float* __restrict__ pl, const float* __restrict__ po, float* __restrict__ ao){
  int h = blockIdx.x, tid = threadIdx.x;
  __shared__ float sm[NCH], sl[NCH], se[NCH];
  if(tid < NCH){ sm[tid] = pm[h*NCH+tid]; sl[tid] = pl[h*NCH+tid]; }
  __syncthreads();
  float M = -1e30f;
  for(int c=0;c<NCH;c++) M = fmaxf(M, sm[c]);
  if(tid < NCH) se[tid] = expf(sm[tid]-M);
  __syncthreads();
  float Lh = 0.f;
  for(int c=0;c<NCH;c++) Lh += sl[c]*se[c];
  float acc = 0.f;
  for(int c=0;c<NCH;c++) acc += po[((size_t)h*NCH + c)*HD + tid]*se[c];
  ao[h*HD + tid] = acc / Lh;
}

// ---- h += rms(y)*g_post_attn; xm = rms(h)*g_pre_ff ----
__global__ __launch_bounds__(256) void post_attn_k(const float* __restrict__ y,
    float* __restrict__ h, const float* __restrict__ gpa,
    const float* __restrict__ gpf, float* __restrict__ xm){
  __shared__ float red[4];
  int tid = threadIdx.x;
  float v[8]; float ss = 0.f;
#pragma unroll
  for(int i=0;i<8;i++){ v[i] = y[tid + i*256]; ss += v[i]*v[i]; }
  ss = blockSum256(ss, red);
  float r1 = rsqrtf(ss*(1.f/DIM) + 1e-6f);
  float hn[8]; float ss2 = 0.f;
#pragma unroll
  for(int i=0;i<8;i++){
    int idx = tid + i*256;
    hn[i] = h[idx] + v[i]*r1*gpa[idx];
    h[idx] = hn[i];
    ss2 += hn[i]*hn[i];
  }
  ss2 = blockSum256(ss2, red);
  float r2 = rsqrtf(ss2*(1.f/DIM) + 1e-6f);
#pragma unroll
  for(int i=0;i<8;i++){ int idx = tid + i*256; xm[idx] = hn[i]*r2*gpf[idx]; }
}

// ---- fused gate/up: t[j] = gelu(Wg[j].xm) * (Wu[j].xm) ----
__global__ __launch_bounds__(256) void gateup_k(const float* __restrict__ Wg,
    const float* __restrict__ Wu, const float* __restrict__ x, float* __restrict__ t){
  __shared__ float xs[DIM];
  for(int i=threadIdx.x; i<DIM/4; i+=256)
    ((float4*)xs)[i] = ((const float4*)x)[i];
  __syncthreads();
  int lane = threadIdx.x & 63, wv = threadIdx.x >> 6;
  int j = blockIdx.x*4 + wv;
  const float4* Gr = (const float4*)(Wg + (size_t)j*DIM);
  const float4* Ur = (const float4*)(Wu + (size_t)j*DIM);
  float ag = 0.f, au = 0.f;
#pragma unroll
  for(int i=0;i<DIM/256;i++){
    float4 b = ((float4*)xs)[lane + i*64];
    float4 a = Gr[lane + i*64];
    ag += a.x*b.x + a.y*b.y + a.z*b.z + a.w*b.w;
    float4 u = Ur[lane + i*64];
    au += u.x*b.x + u.y*b.y + u.z*b.z + u.w*b.w;
  }
  ag = waveAllSum(ag);
  au = waveAllSum(au);
  if(lane==0) t[j] = gelu_tanh(ag)*au;
}

// ---- h += rms(m)*g_post_ff ----
__global__ __launch_bounds__(256) void post_ff_k(const float* __restrict__ mv,
    float* __restrict__ h, const float* __restrict__ gpf){
  __shared__ float red[4];
  int tid = threadIdx.x;
  float v[8]; float ss = 0.f;
#pragma unroll
  for(int i=0;i<8;i++){ v[i] = mv[tid + i*256]; ss += v[i]*v[i]; }
  ss = blockSum256(ss, red);
  float r = rsqrtf(ss*(1.f/DIM) + 1e-6f);
#pragma unroll
  for(int i=0;i<8;i++){ int idx = tid + i*256; h[idx] += v[i]*r*gpf[idx]; }
}

// ---- plg: g[j] = gelu(W[j].h) * pls[j]  (256 rows) ----
__global__ __launch_bounds__(256) void plg_k(const float* __restrict__ W,
    const float* __restrict__ hvec, float* __restrict__ g, const float* __restrict__ pls){
  __shared__ float xs[DIM];
  for(int i=threadIdx.x; i<DIM/4; i+=256)
    ((float4*)xs)[i] = ((const float4*)hvec)[i];
  __syncthreads();
  int lane = threadIdx.x & 63, wv = threadIdx.x >> 6;
  int r = blockIdx.x*4 + wv;
  const float4* Wr = (const float4*)(W + (size_t)r*DIM);
  float acc = 0.f;
#pragma unroll
  for(int i=0;i<DIM/256;i++){
    float4 a = Wr[lane + i*64];
    float4 b = ((float4*)xs)[lane + i*64];
    acc += a.x*b.x + a.y*b.y + a.z*b.z + a.w*b.w;
  }
  acc = waveAllSum(acc);
  if(lane==0) g[r] = gelu_tanh(acc)*pls[r];
}

// ---- h = (h + rms(u)*g_post_pl)*ls; x = rms(h)*g_in_next; optional final out ----
__global__ __launch_bounds__(256) void post_pl_k(const float* __restrict__ u,
    float* __restrict__ h, const float* __restrict__ gpl, const float* __restrict__ lsc,
    const float* __restrict__ gin_next, float* __restrict__ x, float* __restrict__ outh){
  __shared__ float red[4];
  int tid = threadIdx.x;
  float v[8]; float ss = 0.f;
#pragma unroll
  for(int i=0;i<8;i++){ v[i] = u[tid + i*256]; ss += v[i]*v[i]; }
  ss = blockSum256(ss, red);
  float r1 = rsqrtf(ss*(1.f/DIM) + 1e-6f);
  float ls = lsc[0];
  float hn[8]; float ss2 = 0.f;
#pragma unroll
  for(int i=0;i<8;i++){
    int idx = tid + i*256;
    hn[i] = (h[idx] + v[i]*r1*gpl[idx])*ls;
    h[idx] = hn[i];
    ss2 += hn[i]*hn[i];
  }
  ss2 = blockSum256(ss2, red);
  float r2 = rsqrtf(ss2*(1.f/DIM) + 1e-6f);
#pragma unroll
  for(int i=0;i<8;i++){
    int idx = tid + i*256;
    x[idx] = hn[i]*r2*gin_next[idx];
    if(outh) outh[idx] = hn[i];
  }
}

extern "C" void kernel_launch(void* const* d_in, const int* in_sizes, int n_in,
                              void* d_out, int out_size, void* d_ws, size_t ws_size,
                              hipStream_t stream){
  const float* hidden   = (const float*)d_in[0];
  const float* plc      = (const float*)d_in[3];
  const float* cos_s    = (const float*)d_in[4];
  const float* sin_s    = (const float*)d_in[5];
  const float* cos_f    = (const float*)d_in[6];
  const float* sin_f    = (const float*)d_in[7];
  const float* K_in     = (const float*)d_in[8];
  const float* V_in     = (const float*)d_in[9];
  const float* w_q      = (const float*)d_in[10];
  const float* w_k      = (const float*)d_in[11];
  const float* w_v      = (const float*)d_in[12];
  const float* w_o      = (const float*)d_in[13];
  const float* g_in_ln  = (const float*)d_in[14];
  const float* g_q_norm = (const float*)d_in[15];
  const float* g_k_norm = (const float*)d_in[16];
  const float* g_pa_ln  = (const float*)d_in[17];
  const float* g_pf_ln  = (const float*)d_in[18];
  const float* g_ff_ln  = (const float*)d_in[19];
  const float* w_gate   = (const float*)d_in[20];
  const float* w_up     = (const float*)d_in[21];
  const float* w_down   = (const float*)d_in[22];
  const float* w_plg    = (const float*)d_in[23];
  const float* w_plp    = (const float*)d_in[24];
  const float* g_pl_ln  = (const float*)d_in[25];
  const float* l_scal   = (const float*)d_in[26];

  float* out  = (float*)d_out;
  float* outK = out + DIM;
  float* outV = outK + (size_t)NL*NKV*KVL*HD;

  float* ws   = (float*)d_ws;
  float* h    = ws;
  float* x    = ws + 2048;
  float* qkv  = ws + 4096;
  float* q    = ws + 7168;
  float* ao   = ws + 9216;
  float* y    = ws + 11264;
  float* xm   = ws + 13312;
  float* t    = ws + 15360;
  float* mv   = ws + 23552;
  float* gb   = ws + 25600;
  float* u    = ws + 25856;
  float* pm   = ws + 27904;
  float* pl   = ws + 28928;
  float* po   = ws + 29952;

  // Bulk KV cache copy (row POS overwritten per-layer below)
  (void)hipMemcpyAsync(outK, K_in, (size_t)NL*NKV*KVL*HD*sizeof(float),
                       hipMemcpyDeviceToDevice, stream);
  (void)hipMemcpyAsync(outV, V_in, (size_t)NL*NKV*KVL*HD*sizeof(float),
                       hipMemcpyDeviceToDevice, stream);

  initial_k<<<1,256,0,stream>>>(hidden, g_in_ln, h, x);

  for(int l=0;l<NL;l++){
    const float* cosT = (l==4) ? cos_f : cos_s;
    const float* sinT = (l==4) ? sin_f : sin_s;
    float* Kl = outK + (size_t)l*NKV*KVL*HD;
    float* Vl = outV + (size_t)l*NKV*KVL*HD;

    qkv_k<<<768,256,0,stream>>>(w_q + (size_t)l*NH*HD*DIM,
                                w_k + (size_t)l*NKV*HD*DIM,
                                w_v + (size_t)l*NKV*HD*DIM, x, qkv);
    qkvnorm_k<<<12,256,0,stream>>>(qkv, g_q_norm + l*HD, g_k_norm + l*HD,
                                   cosT, sinT, q, Kl, Vl);
    attn_partial_k<<<NKV*NCH,256,0,stream>>>(q, Kl, Vl, pm, pl, po);
    attn_combine_k<<<NH,256,0,stream>>>(pm, pl, po, ao);
    gemv_k<DIM><<<512,256,0,stream>>>(w_o + (size_t)l*DIM*NH*HD, ao, y, DIM);
    post_attn_k<<<1,256,0,stream>>>(y, h, g_pa_ln + l*DIM, g_pf_ln + l*DIM, xm);
    gateup_k<<<FFI/4,256,0,stream>>>(w_gate + (size_t)l*FFI*DIM,
                                     w_up + (size_t)l*FFI*DIM, xm, t);
    gemv_k<FFI><<<512,256,0,stream>>>(w_down + (size_t)l*DIM*FFI, t, mv, DIM);
    post_ff_k<<<1,256,0,stream>>>(mv, h, g_ff_ln + l*DIM);
    plg_k<<<PLD/4,256,0,stream>>>(w_plg + (size_t)l*PLD*DIM, h, gb, plc + l*PLD);
    gemv_k<PLD><<<512,256,0,stream>>>(w_plp + (size_t)l*DIM*PLD, gb, u, DIM);
    post_pl_k<<<1,256,0,stream>>>(u, h, g_pl_ln + l*DIM, l_scal + l,
                                  g_in_ln + ((l+1)%NL)*DIM, x,
                                  (l==NL-1) ? out : nullptr);
  }
}